// Round 3
// baseline (404.701 us; speedup 1.0000x reference)
//
#include <hip/hip_runtime.h>
#include <hip/hip_bf16.h>

#define DWT_LEN_C 84
#define TDIM 64
#define INNER 4096   // 64 * 8 * 8
#define KOUT 16
#define NCHUNK 16    // column chunks of 256 floats
#define CHW 256      // columns per chunk

typedef const __attribute__((address_space(1))) void* gptr_t;
typedef __attribute__((address_space(3))) void* lptr_t;
#define GLOAD_LDS16(g, l) __builtin_amdgcn_global_load_lds((gptr_t)(g), (lptr_t)(l), 16, 0, 0)

// db4 analysis filters
__device__ const float c_dec_lo[8] = {-0.010597401784997278f, 0.032883011666982945f, 0.030841381835986965f,
                                      -0.18703481171888114f, -0.02798376941698385f, 0.6308807679295904f,
                                      0.7148465705525415f, 0.23037781330885523f};
__device__ const float c_dec_hi[8] = {-0.23037781330885523f, 0.7148465705525415f, -0.6308807679295904f,
                                      -0.02798376941698385f, 0.18703481171888114f, 0.030841381835986965f,
                                      -0.032883011666982945f, -0.010597401784997278f};

// Single-level analysis filter bank (reflect pad; left pad 6 for our sizes).
__device__ void afb1d_col(const float* v, int N, float* lo, float* hi, int M) {
    for (int i = 0; i < M; ++i) {
        float slo = 0.f, shi = 0.f;
        for (int j = 0; j < 8; ++j) {
            int idx = 2 * i + j - 6;
            if (idx < 0) idx = -idx;                  // reflect (exclude edge)
            if (idx >= N) idx = 2 * N - 2 - idx;
            float c = v[idx];
            slo = fmaf(c, c_dec_lo[7 - j], slo);      // conv = corr with reversed filter
            shi = fmaf(c, c_dec_hi[7 - j], shi);
        }
        lo[i] = slo; hi[i] = shi;
    }
}

// Fused setup: rebuild W_dwt[84][64] in LDS, then write W_eff in CHUNKED layout:
// Weff[(col>>8)][k][col&255], col = t*64+hw.  (16 KB contiguous per chunk)
__global__ __launch_bounds__(256) void build_weff_fused(const float* __restrict__ conv_w,
                                                        float* __restrict__ Weff) {
    __shared__ float Wd[DWT_LEN_C][TDIM];
    const int t0 = threadIdx.x;
    if (t0 < TDIM) {
        float v[64];
        for (int n = 0; n < 64; ++n) v[n] = (n == t0) ? 1.f : 0.f;
        float lo1[35], hi1[35], lo2[21], hi2[21], lo3[14], hi3[14];
        afb1d_col(v, 64, lo1, hi1, 35);
        afb1d_col(lo1, 35, lo2, hi2, 21);
        afb1d_col(lo2, 21, lo3, hi3, 14);
        for (int i = 0; i < 14; ++i) Wd[i][t0] = lo3[i];
        for (int i = 0; i < 35; ++i) Wd[14 + i][t0] = hi1[i];
        for (int i = 0; i < 21; ++i) Wd[49 + i][t0] = hi2[i];
        for (int i = 0; i < 14; ++i) Wd[70 + i][t0] = hi3[i];
    }
    __syncthreads();

    const int idx = blockIdx.x * 256 + threadIdx.x;    // k*4096 + col
    const int k = idx >> 12;
    const int col = idx & 4095;
    const int t = col >> 6;
    const int hw = col & 63;
    float s = 0.f;
    const float* cw = conv_w + (size_t)k * DWT_LEN_C * 64 + hw;
#pragma unroll 4
    for (int dd = 0; dd < DWT_LEN_C; ++dd)
        s = fmaf(cw[dd * 64], Wd[dd][t], s);
    Weff[((col >> 8) * KOUT + k) * CHW + (col & 255)] = s;
}

// Main GEMV: out[b,k] = leakyrelu( dot(x[b,:4096], Weff[k,:4096]) + bias[k] )
// 4 waves/block, 4 rows/wave. W chunk (16 KB) staged to LDS per j, double-buffered
// via global_load_lds; lane l covers cols l*4..l*4+3 of each chunk.
__global__ __launch_bounds__(256, 4) void dwt_gemv(const float* __restrict__ x,
                                                   const float* __restrict__ W,  // chunked [16][16][256]
                                                   const float* __restrict__ bias,
                                                   float* __restrict__ out, int B) {
    __shared__ __align__(16) float Wlds[2][KOUT * CHW];   // 2 x 16 KB
    const int lane = threadIdx.x & 63;
    const int wid = threadIdx.x >> 6;
    const int group = blockIdx.x * 4 + wid;
    const long rowbase = (long)group * 4;

    const float* xp[4];
#pragma unroll
    for (int r = 0; r < 4; ++r) {
        long row = rowbase + r;
        if (row > B - 1) row = B - 1;   // clamped rows never stored
        xp[r] = x + row * (long)INNER;
    }

    float a[64];
#pragma unroll
    for (int i = 0; i < 64; ++i) a[i] = 0.f;

    const int lane4 = lane * 4;
    const int sofs = wid * 1024 + lane4;   // this thread's staging slot (floats), i-stride 256

    // stage chunk 0 into buf 0 (4 KB per wave, 4 x 16B per lane)
    {
        const float* src = W + sofs;
        float* dst = &Wlds[0][sofs];
#pragma unroll
        for (int i = 0; i < 4; ++i)
            GLOAD_LDS16(src + i * 256, dst + i * 256);
    }
    // prologue x load j=0
    float4 xv[4];
#pragma unroll
    for (int r = 0; r < 4; ++r) xv[r] = *(const float4*)(xp[r] + lane4);
    __syncthreads();   // drains vmcnt -> chunk 0 (and xv) ready

#pragma unroll 1
    for (int j = 0; j < NCHUNK; ++j) {
        const int cur = j & 1;
        // stage next chunk into the other buffer (async, completes by next barrier)
        if (j < NCHUNK - 1) {
            const float* src = W + (j + 1) * (KOUT * CHW) + sofs;
            float* dst = &Wlds[cur ^ 1][sofs];
#pragma unroll
            for (int i = 0; i < 4; ++i)
                GLOAD_LDS16(src + i * 256, dst + i * 256);
        }
        // prefetch next j's x while computing current
        float4 xn[4];
        if (j < NCHUNK - 1) {
            const int off = (j + 1) * 256 + lane4;
#pragma unroll
            for (int r = 0; r < 4; ++r) xn[r] = *(const float4*)(xp[r] + off);
        }
        // compute current chunk from LDS
#pragma unroll
        for (int k = 0; k < 16; ++k) {
            float4 wv = *(const float4*)&Wlds[cur][k * CHW + lane4];
#pragma unroll
            for (int r = 0; r < 4; ++r) {
                float s = a[r * 16 + k];
                s = fmaf(xv[r].x, wv.x, s);
                s = fmaf(xv[r].y, wv.y, s);
                s = fmaf(xv[r].z, wv.z, s);
                s = fmaf(xv[r].w, wv.w, s);
                a[r * 16 + k] = s;
            }
        }
        if (j < NCHUNK - 1) {
#pragma unroll
            for (int r = 0; r < 4; ++r) xv[r] = xn[r];
            __syncthreads();   // staged chunk complete in all waves before next compute
        }
    }

    // Butterfly transpose-reduce: lane l ends with full sum of value bitrev6(l).
#pragma unroll
    for (int s = 0; s < 6; ++s) {
        const int m = 1 << s;
        const int h = 32 >> s;
#pragma unroll
        for (int v = 0; v < h; ++v) {
            float send = (lane & m) ? a[v] : a[v + h];
            float recv = __shfl_xor(send, m, 64);
            a[v] = ((lane & m) ? a[v + h] : a[v]) + recv;
        }
    }

    const unsigned vidx = __brev((unsigned)lane) >> 26;  // bitrev6
    const int k = vidx & 15;
    const int r = vidx >> 4;
    const long row = rowbase + r;
    if (row < B) {
        float val = a[0] + bias[k];
        val = (val >= 0.f) ? val : 1e-3f * val;
        out[row * KOUT + k] = val;
    }
}

extern "C" void kernel_launch(void* const* d_in, const int* in_sizes, int n_in,
                              void* d_out, int out_size, void* d_ws, size_t ws_size,
                              hipStream_t stream) {
    const float* x      = (const float*)d_in[0];
    const float* conv_w = (const float*)d_in[1];
    const float* conv_b = (const float*)d_in[2];
    float* out = (float*)d_out;
    const int B = in_sizes[0] / INNER;

    float* Weff = (float*)d_ws;                         // 16*4096 floats = 256 KB, chunked

    build_weff_fused<<<(KOUT * INNER) / 256, 256, 0, stream>>>(conv_w, Weff);

    const int groups = (B + 3) / 4;        // 4 rows per wave
    const int blocks = (groups + 3) / 4;   // 4 waves per block
    dwt_gemv<<<blocks, 256, 0, stream>>>(x, Weff, conv_b, out, B);
}

// Round 4
// 61.475 us; speedup vs baseline: 6.5832x; 6.5832x over previous
//
#include <hip/hip_runtime.h>
#include <hip/hip_bf16.h>

#define DWT_LEN_C 84
#define TDIM 64
#define INNER 4096   // 64 * 8 * 8
#define KOUT 16
#define QCOLS 1024   // K-quarter width

typedef __attribute__((ext_vector_type(8))) short short8;
typedef __attribute__((ext_vector_type(4))) float floatx4;

__device__ __forceinline__ unsigned short bf16_rne(float f) {
    unsigned u = __float_as_uint(f);
    unsigned r = u + 0x7fffu + ((u >> 16) & 1u);
    return (unsigned short)(r >> 16);
}

// db4 analysis filters
__device__ const float c_dec_lo[8] = {-0.010597401784997278f, 0.032883011666982945f, 0.030841381835986965f,
                                      -0.18703481171888114f, -0.02798376941698385f, 0.6308807679295904f,
                                      0.7148465705525415f, 0.23037781330885523f};
__device__ const float c_dec_hi[8] = {-0.23037781330885523f, 0.7148465705525415f, -0.6308807679295904f,
                                      -0.02798376941698385f, 0.18703481171888114f, 0.030841381835986965f,
                                      -0.032883011666982945f, -0.010597401784997278f};

// Single-level analysis filter bank (reflect pad; left pad 6 for our sizes).
__device__ void afb1d_col(const float* v, int N, float* lo, float* hi, int M) {
    for (int i = 0; i < M; ++i) {
        float slo = 0.f, shi = 0.f;
        for (int j = 0; j < 8; ++j) {
            int idx = 2 * i + j - 6;
            if (idx < 0) idx = -idx;                  // reflect (exclude edge)
            if (idx >= N) idx = 2 * N - 2 - idx;
            float c = v[idx];
            slo = fmaf(c, c_dec_lo[7 - j], slo);      // conv = corr with reversed filter
            shi = fmaf(c, c_dec_hi[7 - j], shi);
        }
        lo[i] = slo; hi[i] = shi;
    }
}

// Fused setup: rebuild W_dwt[84][64] in LDS, then emit W_eff as bf16 [KOUT][INNER]:
// Weff[k][t*64+hw] = sum_dd conv_w[k][dd][hw] * W_dwt[dd][t]  (fp32 accum, one RNE round)
__global__ __launch_bounds__(256) void build_weff_bf16(const float* __restrict__ conv_w,
                                                       unsigned short* __restrict__ Wb) {
    __shared__ float Wd[DWT_LEN_C][TDIM];
    const int t0 = threadIdx.x;
    if (t0 < TDIM) {
        float v[64];
        for (int n = 0; n < 64; ++n) v[n] = (n == t0) ? 1.f : 0.f;
        float lo1[35], hi1[35], lo2[21], hi2[21], lo3[14], hi3[14];
        afb1d_col(v, 64, lo1, hi1, 35);
        afb1d_col(lo1, 35, lo2, hi2, 21);
        afb1d_col(lo2, 21, lo3, hi3, 14);
        for (int i = 0; i < 14; ++i) Wd[i][t0] = lo3[i];
        for (int i = 0; i < 35; ++i) Wd[14 + i][t0] = hi1[i];
        for (int i = 0; i < 21; ++i) Wd[49 + i][t0] = hi2[i];
        for (int i = 0; i < 14; ++i) Wd[70 + i][t0] = hi3[i];
    }
    __syncthreads();

    const int idx = blockIdx.x * 256 + threadIdx.x;    // k*4096 + col
    const int k = idx >> 12;
    const int col = idx & 4095;
    const int t = col >> 6;
    const int hw = col & 63;
    float s = 0.f;
    const float* cw = conv_w + (size_t)k * DWT_LEN_C * 64 + hw;
#pragma unroll 4
    for (int dd = 0; dd < DWT_LEN_C; ++dd)
        s = fmaf(cw[dd * 64], Wd[dd][t], s);
    Wb[idx] = bf16_rne(s);
}

// MFMA GEMM: M=B rows, N=16 outputs, K-quarter of 1024 cols per block.
// Block: 256 thr / 4 waves, 64 rows (16 rows per wave). W quarter (16x1024 bf16 =
// 32 KB) staged once into LDS, XOR-swizzled for conflict-free ds_read_b128.
// partial[kq][row][16] written; no atomics.
__global__ __launch_bounds__(256) void dwt_mfma(const float* __restrict__ x,
                                                const unsigned short* __restrict__ Wb,
                                                float* __restrict__ partial, int B) {
    __shared__ __align__(16) unsigned short Wlds[KOUT * QCOLS];   // 32 KB
    const int t = threadIdx.x;
    const int rowgroup = blockIdx.x >> 2;
    const int kq = blockIdx.x & 3;

    // Stage: thread t loads row n = t&15, cols c0..c0+63 (128 B contiguous),
    // writes swizzled (group-of-8 XOR (n&7)*8) -> 2-way-max bank aliasing.
    {
        const int n = t & 15;
        const int c0 = (t >> 4) * 64;
        const unsigned short* src = Wb + n * INNER + kq * QCOLS + c0;
#pragma unroll
        for (int g = 0; g < 8; ++g) {
            const int c = c0 + g * 8;
            *(short8*)&Wlds[n * QCOLS + (c ^ ((n & 7) * 8))] = *(const short8*)(src + g * 8);
        }
    }
    __syncthreads();

    const int lane = t & 63;
    const int wid = t >> 6;
    const int qg = lane >> 4;         // K-subgroup 0..3
    const int mrow = lane & 15;       // M row within tile (A) == N col (B)
    const int rowbase = rowgroup * 64 + wid * 16;
    const float* xrow = x + (size_t)(rowbase + mrow) * INNER + kq * QCOLS;
    const unsigned short* wrow = &Wlds[mrow * QCOLS];
    const int swz = (mrow & 7) * 8;

    floatx4 acc = {0.f, 0.f, 0.f, 0.f};
#pragma unroll 4
    for (int step = 0; step < 32; ++step) {
        const int col = step * 32 + qg * 8;          // this lane's 8 K-elements
        const float4 lo = *(const float4*)(xrow + col);
        const float4 hi = *(const float4*)(xrow + col + 4);
        short8 a;
        a[0] = (short)bf16_rne(lo.x); a[1] = (short)bf16_rne(lo.y);
        a[2] = (short)bf16_rne(lo.z); a[3] = (short)bf16_rne(lo.w);
        a[4] = (short)bf16_rne(hi.x); a[5] = (short)bf16_rne(hi.y);
        a[6] = (short)bf16_rne(hi.z); a[7] = (short)bf16_rne(hi.w);
        const short8 b = *(const short8*)(wrow + (col ^ swz));
        acc = __builtin_amdgcn_mfma_f32_16x16x32_bf16(a, b, acc, 0, 0, 0);
    }

    // C mapping (m89-verified): col = lane&15 (= N = kout), row = (lane>>4)*4 + reg
    const int orow = rowbase + qg * 4;
    float* pq = partial + (size_t)kq * B * KOUT;
#pragma unroll
    for (int r = 0; r < 4; ++r)
        pq[(size_t)(orow + r) * KOUT + mrow] = acc[r];
}

// Sum 4 K-quarter partials + bias, LeakyReLU, write out.
__global__ __launch_bounds__(256) void finish(const float* __restrict__ partial,
                                              const float* __restrict__ bias,
                                              float* __restrict__ out, int B) {
    const int idx = blockIdx.x * 256 + threadIdx.x;
    if (idx >= B * KOUT) return;
    const size_t stride = (size_t)B * KOUT;
    float s = partial[idx] + partial[idx + stride] + partial[idx + 2 * stride] + partial[idx + 3 * stride];
    s += bias[idx & 15];
    out[idx] = (s >= 0.f) ? s : 1e-3f * s;
}

extern "C" void kernel_launch(void* const* d_in, const int* in_sizes, int n_in,
                              void* d_out, int out_size, void* d_ws, size_t ws_size,
                              hipStream_t stream) {
    const float* x      = (const float*)d_in[0];
    const float* conv_w = (const float*)d_in[1];
    const float* conv_b = (const float*)d_in[2];
    float* out = (float*)d_out;
    const int B = in_sizes[0] / INNER;   // 16384 (multiple of 64)

    float* partial = (float*)d_ws;                              // 4 * B * 16 * 4B = 4 MB
    unsigned short* Wb = (unsigned short*)((char*)d_ws + ((size_t)4 << 20));  // 128 KB bf16

    build_weff_bf16<<<(KOUT * INNER) / 256, 256, 0, stream>>>(conv_w, Wb);
    dwt_mfma<<<(B / 64) * 4, 256, 0, stream>>>(x, Wb, partial, B);
    finish<<<(B * KOUT + 255) / 256, 256, 0, stream>>>(partial, conv_b, out, B);
}

// Round 5
// 59.113 us; speedup vs baseline: 6.8462x; 1.0400x over previous
//
#include <hip/hip_runtime.h>
#include <hip/hip_bf16.h>

#define DWT_LEN_C 84
#define TDIM 64
#define INNER 4096   // 64 * 8 * 8
#define KOUT 16
#define KSPLIT 8
#define QCOLS 512    // K-chunk width per block (INNER / KSPLIT)
#define STEPS 16     // QCOLS / 32

typedef __attribute__((ext_vector_type(8))) short short8;
typedef __attribute__((ext_vector_type(4))) float floatx4;

__device__ __forceinline__ unsigned short bf16_rne(float f) {
    unsigned u = __float_as_uint(f);
    unsigned r = u + 0x7fffu + ((u >> 16) & 1u);
    return (unsigned short)(r >> 16);
}

// db4 analysis filters
__device__ const float c_dec_lo[8] = {-0.010597401784997278f, 0.032883011666982945f, 0.030841381835986965f,
                                      -0.18703481171888114f, -0.02798376941698385f, 0.6308807679295904f,
                                      0.7148465705525415f, 0.23037781330885523f};
__device__ const float c_dec_hi[8] = {-0.23037781330885523f, 0.7148465705525415f, -0.6308807679295904f,
                                      -0.02798376941698385f, 0.18703481171888114f, 0.030841381835986965f,
                                      -0.032883011666982945f, -0.010597401784997278f};

// Single-level analysis filter bank (reflect pad; left pad 6 for our sizes).
__device__ void afb1d_col(const float* v, int N, float* lo, float* hi, int M) {
    for (int i = 0; i < M; ++i) {
        float slo = 0.f, shi = 0.f;
        for (int j = 0; j < 8; ++j) {
            int idx = 2 * i + j - 6;
            if (idx < 0) idx = -idx;                  // reflect (exclude edge)
            if (idx >= N) idx = 2 * N - 2 - idx;
            float c = v[idx];
            slo = fmaf(c, c_dec_lo[7 - j], slo);      // conv = corr with reversed filter
            shi = fmaf(c, c_dec_hi[7 - j], shi);
        }
        lo[i] = slo; hi[i] = shi;
    }
}

// Fused setup: rebuild W_dwt[84][64] in LDS, then emit W_eff as bf16 [KOUT][INNER]
__global__ __launch_bounds__(256) void build_weff_bf16(const float* __restrict__ conv_w,
                                                       unsigned short* __restrict__ Wb) {
    __shared__ float Wd[DWT_LEN_C][TDIM];
    const int t0 = threadIdx.x;
    if (t0 < TDIM) {
        float v[64];
        for (int n = 0; n < 64; ++n) v[n] = (n == t0) ? 1.f : 0.f;
        float lo1[35], hi1[35], lo2[21], hi2[21], lo3[14], hi3[14];
        afb1d_col(v, 64, lo1, hi1, 35);
        afb1d_col(lo1, 35, lo2, hi2, 21);
        afb1d_col(lo2, 21, lo3, hi3, 14);
        for (int i = 0; i < 14; ++i) Wd[i][t0] = lo3[i];
        for (int i = 0; i < 35; ++i) Wd[14 + i][t0] = hi1[i];
        for (int i = 0; i < 21; ++i) Wd[49 + i][t0] = hi2[i];
        for (int i = 0; i < 14; ++i) Wd[70 + i][t0] = hi3[i];
    }
    __syncthreads();

    const int idx = blockIdx.x * 256 + threadIdx.x;    // k*4096 + col
    const int k = idx >> 12;
    const int col = idx & 4095;
    const int t = col >> 6;
    const int hw = col & 63;
    float s = 0.f;
    const float* cw = conv_w + (size_t)k * DWT_LEN_C * 64 + hw;
#pragma unroll 4
    for (int dd = 0; dd < DWT_LEN_C; ++dd)
        s = fmaf(cw[dd * 64], Wd[dd][t], s);
    Wb[idx] = bf16_rne(s);
}

// MFMA GEMM: M=B rows, N=16 outputs, K-chunk of 512 cols per block (KSPLIT=8).
// Block: 256 thr / 4 waves, 64 rows (16 per wave). W chunk (16x512 bf16 = 16 KB)
// staged once into LDS, XOR-swizzled for conflict-free ds_read_b128.
// launch_bounds(256,6): 24 waves/CU resident for latency hiding; VGPR cap 84.
__global__ __launch_bounds__(256, 6) void dwt_mfma(const float* __restrict__ x,
                                                   const unsigned short* __restrict__ Wb,
                                                   float* __restrict__ partial, int B) {
    __shared__ __align__(16) unsigned short Wlds[KOUT * QCOLS];   // 16 KB
    const int t = threadIdx.x;
    const int rowgroup = blockIdx.x >> 3;
    const int kq = blockIdx.x & 7;

    // Stage: thread t loads row n = t&15, cols c0..c0+31 (64 B contiguous),
    // writes swizzled (short8-group XOR (n&7)*8) -> 2-way-max bank aliasing.
    {
        const int n = t & 15;
        const int c0 = (t >> 4) * 32;
        const unsigned short* src = Wb + n * INNER + kq * QCOLS + c0;
#pragma unroll
        for (int g = 0; g < 4; ++g) {
            const int c = c0 + g * 8;
            *(short8*)&Wlds[n * QCOLS + (c ^ ((n & 7) * 8))] = *(const short8*)(src + g * 8);
        }
    }
    __syncthreads();

    const int lane = t & 63;
    const int wid = t >> 6;
    const int qg = lane >> 4;         // K-subgroup 0..3
    const int mrow = lane & 15;       // M row within tile (A) == N col (B)
    const int rowbase = rowgroup * 64 + wid * 16;
    const float* xrow = x + (size_t)(rowbase + mrow) * INNER + kq * QCOLS;
    const unsigned short* wrow = &Wlds[mrow * QCOLS];
    const int swz = (mrow & 7) * 8;

    floatx4 acc = {0.f, 0.f, 0.f, 0.f};
#pragma unroll 4
    for (int step = 0; step < STEPS; ++step) {
        const int col = step * 32 + qg * 8;          // this lane's 8 K-elements
        const float4 lo = *(const float4*)(xrow + col);
        const float4 hi = *(const float4*)(xrow + col + 4);
        short8 a;
        a[0] = (short)bf16_rne(lo.x); a[1] = (short)bf16_rne(lo.y);
        a[2] = (short)bf16_rne(lo.z); a[3] = (short)bf16_rne(lo.w);
        a[4] = (short)bf16_rne(hi.x); a[5] = (short)bf16_rne(hi.y);
        a[6] = (short)bf16_rne(hi.z); a[7] = (short)bf16_rne(hi.w);
        const short8 b = *(const short8*)(wrow + (col ^ swz));
        acc = __builtin_amdgcn_mfma_f32_16x16x32_bf16(a, b, acc, 0, 0, 0);
    }

    // C mapping (m89-verified): col = lane&15 (= kout), row = (lane>>4)*4 + reg
    const int orow = rowbase + qg * 4;
    float* pq = partial + (size_t)kq * B * KOUT;
#pragma unroll
    for (int r = 0; r < 4; ++r)
        pq[(size_t)(orow + r) * KOUT + mrow] = acc[r];
}

// Sum KSPLIT partials + bias, LeakyReLU, write out. float4-vectorized.
__global__ __launch_bounds__(256) void finish(const float* __restrict__ partial,
                                              const float* __restrict__ bias,
                                              float* __restrict__ out, int B) {
    const int idx4 = (blockIdx.x * 256 + threadIdx.x) * 4;
    if (idx4 >= B * KOUT) return;
    const size_t stride = (size_t)B * KOUT;
    float4 s = *(const float4*)(partial + idx4);
#pragma unroll
    for (int kq = 1; kq < KSPLIT; ++kq) {
        float4 p = *(const float4*)(partial + kq * stride + idx4);
        s.x += p.x; s.y += p.y; s.z += p.z; s.w += p.w;
    }
    const float4 bb = *(const float4*)(bias + (idx4 & 15));
    s.x += bb.x; s.y += bb.y; s.z += bb.z; s.w += bb.w;
    s.x = (s.x >= 0.f) ? s.x : 1e-3f * s.x;
    s.y = (s.y >= 0.f) ? s.y : 1e-3f * s.y;
    s.z = (s.z >= 0.f) ? s.z : 1e-3f * s.z;
    s.w = (s.w >= 0.f) ? s.w : 1e-3f * s.w;
    *(float4*)(out + idx4) = s;
}

extern "C" void kernel_launch(void* const* d_in, const int* in_sizes, int n_in,
                              void* d_out, int out_size, void* d_ws, size_t ws_size,
                              hipStream_t stream) {
    const float* x      = (const float*)d_in[0];
    const float* conv_w = (const float*)d_in[1];
    const float* conv_b = (const float*)d_in[2];
    float* out = (float*)d_out;
    const int B = in_sizes[0] / INNER;   // 16384 (multiple of 64)

    float* partial = (float*)d_ws;                              // KSPLIT * B * 16 * 4B = 8 MB
    unsigned short* Wb = (unsigned short*)((char*)d_ws + ((size_t)16 << 20));  // 128 KB bf16

    build_weff_bf16<<<(KOUT * INNER) / 256, 256, 0, stream>>>(conv_w, Wb);
    dwt_mfma<<<(B / 64) * KSPLIT, 256, 0, stream>>>(x, Wb, partial, B);
    finish<<<(B * KOUT / 4 + 255) / 256, 256, 0, stream>>>(partial, conv_b, out, B);
}